// Round 3
// baseline (237.739 us; speedup 1.0000x reference)
//
#include <hip/hip_runtime.h>

// Problem constants
constexpr int   kAtoms  = 5000;
constexpr int   kPairs  = 160000;
constexpr int   KD      = 128;   // K
constexpr int   NB      = 8;     // N_BASIS
constexpr int   RH      = 32;    // RAD_HIDDEN
constexpr float kCutoff = 5.0f;
constexpr float kPi     = 3.14159265358979323846f;
constexpr float C1 = 0.2f * 0.1767767f;   // INIT_SCALE * MSG_SCALE
constexpr float C2 = 1.2f * 0.1767767f;   // (1+INIT_SCALE) * MSG_SCALE
constexpr int   CHUNK = 32;               // ~mean neighbor count (Poisson 32)

__device__ __forceinline__ float silu(float x) { return x / (1.0f + __expf(-x)); }

// Only the l=0 channel reaches the output; l>=1 / sph / U2 are dead code.
//   F0[a][k] = C1 * sum_p R0_p[k]*e_spec[k];  G0 = F0+F0^2*mix
//   D[a][k]  = sum_p Re0_p[k]*G0[nbr_p][k];   n = G0+C2*D;  V = n+n^2*emix
//   out = head MLP(V)
// f0 uses species factoring:
//   F0[a][k] = C1*( b2[k]*sum_s n_s*e_s[k] + sum_s e_s[k]*sum_j w2[j][k]*H_s[j] )
//   with H_s[j] = sum_{p in s} h_p[j]   (no per-pair k loop at all)

// ---------------------------------------------------------------------------
__global__ __launch_bounds__(256) void hist_kernel(
    const int* __restrict__ ctr, int* __restrict__ cnt)
{
    int p = blockIdx.x * 256 + threadIdx.x;
    atomicAdd(cnt + ctr[p], 1);
}

// ---------------------------------------------------------------------------
__global__ __launch_bounds__(1024) void scan_kernel(
    const int* __restrict__ cnt, int* __restrict__ off, int* __restrict__ cur)
{
    __shared__ int s_part[1024];
    const int CH = 5;                       // 1024*5 = 5120 >= 5000
    int t = threadIdx.x;
    int base = t * CH;
    int loc[CH];
    int run = 0;
    #pragma unroll
    for (int i = 0; i < CH; i++) {
        int idx = base + i;
        int v = (idx < kAtoms) ? cnt[idx] : 0;
        loc[i] = run;
        run += v;
    }
    s_part[t] = run;
    __syncthreads();
    for (int st = 1; st < 1024; st <<= 1) {
        int v = (t >= st) ? s_part[t - st] : 0;
        __syncthreads();
        s_part[t] += v;
        __syncthreads();
    }
    int excl = (t > 0) ? s_part[t - 1] : 0;
    #pragma unroll
    for (int i = 0; i < CH; i++) {
        int idx = base + i;
        if (idx < kAtoms) { off[idx] = excl + loc[i]; cur[idx] = excl + loc[i]; }
    }
    if (t == 1023) off[kAtoms] = s_part[1023];
}

// ---------------------------------------------------------------------------
__global__ __launch_bounds__(256) void build_kernel(
    const float* __restrict__ pos, const float* __restrict__ cells,
    const int* __restrict__ species, const int* __restrict__ shifts,
    const int* __restrict__ ctr, const int* __restrict__ nbr,
    const int* __restrict__ spair,
    int* __restrict__ cur, int* __restrict__ nbrs_s, int* __restrict__ specs_s,
    float* __restrict__ rbf_s)
{
    int p = blockIdx.x * 256 + threadIdx.x;
    int ci = ctr[p], ni = nbr[p], sp = spair[p];
    float s0 = (float)shifts[p * 3 + 0] - 1.0f;
    float s1 = (float)shifts[p * 3 + 1] - 1.0f;
    float s2 = (float)shifts[p * 3 + 2] - 1.0f;
    const float* C = cells + sp * 9;
    float vx = pos[ni * 3 + 0] - pos[ci * 3 + 0] + s0 * C[0] + s1 * C[3] + s2 * C[6];
    float vy = pos[ni * 3 + 1] - pos[ci * 3 + 1] + s0 * C[1] + s1 * C[4] + s2 * C[7];
    float vz = pos[ni * 3 + 2] - pos[ci * 3 + 2] + s0 * C[2] + s1 * C[5] + s2 * C[8];
    float d = sqrtf(vx * vx + vy * vy + vz * vz + 1e-12f);
    float fcut = (d < kCutoff) ? 0.5f * (__cosf(kPi * d / kCutoff) + 1.0f) : 0.0f;

    int slot = atomicAdd(cur + ci, 1);
    nbrs_s[slot]  = ni;
    specs_s[slot] = species[ni];

    float r[NB];
    #pragma unroll
    for (int i = 0; i < NB; i++) {
        float tt = d - (kCutoff / (NB - 1)) * (float)i;
        r[i] = __expf(-2.0f * tt * tt) * fcut;
    }
    float4* dst = (float4*)(rbf_s + (size_t)slot * NB);
    dst[0] = make_float4(r[0], r[1], r[2], r[3]);
    dst[1] = make_float4(r[4], r[5], r[6], r[7]);
}

// ---------------------------------------------------------------------------
// K4: species-factored F0 + G0 store. 128 threads = 2 waves, one atom per
// wave (per-wave private LDS partials; all __syncthreads at uniform points).
// ---------------------------------------------------------------------------
__global__ __launch_bounds__(128) void f0_kernel(
    const float* __restrict__ rbf_s, const int* __restrict__ specs_s,
    const int* __restrict__ off,
    const float* __restrict__ embed,
    const float* __restrict__ w1, const float* __restrict__ b1,
    const float* __restrict__ w2, const float* __restrict__ b2,
    const float* __restrict__ mix,
    float* __restrict__ G0)
{
    __shared__ float s_w1[NB][RH];
    __shared__ float s_b1v[RH];
    __shared__ float s_Hp[2][2][4][RH];   // [wave][group][spec][j]
    __shared__ float s_H[2][4][RH];       // [wave][spec][j]
    __shared__ float s_np[2][2][4];
    __shared__ float s_nc[2][4];

    int t = threadIdx.x;          // 0..127
    int w = t >> 6;               // wave id (atom within block)
    int t64 = t & 63;
    for (int idx = t; idx < NB * RH; idx += 128)
        s_w1[idx >> 5][idx & 31] = w1[idx];
    if (t < RH) s_b1v[t] = b1[t];
    __syncthreads();

    int a = blockIdx.x * 2 + w;
    int start = off[a], m = off[a + 1] - start;

    int g = t64 >> 5, j = t64 & 31;
    float H0 = 0, H1 = 0, H2 = 0, H3 = 0;
    int   n0 = 0, n1 = 0, n2 = 0, n3 = 0;
    float b1j = s_b1v[j];
    for (int pr = g; pr < m; pr += 2) {
        const float* rb = rbf_s + (size_t)(start + pr) * NB;
        float acc = b1j;
        #pragma unroll
        for (int i = 0; i < NB; i++) acc += rb[i] * s_w1[i][j];
        float h = silu(acc);
        int s = specs_s[start + pr];
        H0 += (s == 0) ? h : 0.0f;  H1 += (s == 1) ? h : 0.0f;
        H2 += (s == 2) ? h : 0.0f;  H3 += (s == 3) ? h : 0.0f;
        n0 += (s == 0); n1 += (s == 1); n2 += (s == 2); n3 += (s == 3);
    }
    s_Hp[w][g][0][j] = H0; s_Hp[w][g][1][j] = H1;
    s_Hp[w][g][2][j] = H2; s_Hp[w][g][3][j] = H3;
    if (j == 0) {
        s_np[w][g][0] = (float)n0; s_np[w][g][1] = (float)n1;
        s_np[w][g][2] = (float)n2; s_np[w][g][3] = (float)n3;
    }
    __syncthreads();
    for (int e = t64; e < 4 * RH; e += 64) {
        int s = e >> 5, jj = e & 31;
        s_H[w][s][jj] = s_Hp[w][0][s][jj] + s_Hp[w][1][s][jj];
    }
    if (t64 < 4) s_nc[w][t64] = s_np[w][0][t64] + s_np[w][1][t64];
    __syncthreads();

    float nc0 = s_nc[w][0], nc1 = s_nc[w][1], nc2 = s_nc[w][2], nc3 = s_nc[w][3];
    #pragma unroll
    for (int half = 0; half < 2; half++) {
        int k = t64 + 64 * half;
        float e0 = embed[0 * KD + k], e1 = embed[1 * KD + k];
        float e2 = embed[2 * KD + k], e3 = embed[3 * KD + k];
        float P0 = 0, P1 = 0, P2 = 0, P3 = 0;
        #pragma unroll 2
        for (int jq = 0; jq < RH / 4; jq++) {
            float4 h0 = *(const float4*)&s_H[w][0][4 * jq];
            float4 h1 = *(const float4*)&s_H[w][1][4 * jq];
            float4 h2 = *(const float4*)&s_H[w][2][4 * jq];
            float4 h3 = *(const float4*)&s_H[w][3][4 * jq];
            float wa = w2[(4 * jq + 0) * (3 * KD) + k];
            float wb = w2[(4 * jq + 1) * (3 * KD) + k];
            float wc = w2[(4 * jq + 2) * (3 * KD) + k];
            float wd = w2[(4 * jq + 3) * (3 * KD) + k];
            P0 += h0.x * wa + h0.y * wb + h0.z * wc + h0.w * wd;
            P1 += h1.x * wa + h1.y * wb + h1.z * wc + h1.w * wd;
            P2 += h2.x * wa + h2.y * wb + h2.z * wc + h2.w * wd;
            P3 += h3.x * wa + h3.y * wb + h3.z * wc + h3.w * wd;
        }
        float F = b2[k] * (nc0 * e0 + nc1 * e1 + nc2 * e2 + nc3 * e3)
                + e0 * P0 + e1 * P1 + e2 * P2 + e3 * P3;
        float F0v = C1 * F;
        G0[(size_t)a * KD + k] = F0v + F0v * F0v * mix[k];
    }
}

// ---------------------------------------------------------------------------
// K5: D0 + V. Round-0 single-wave structure, but split-k: 2 blocks per atom
// (kh = blockIdx.x & 1), 64 threads, each lane owns ONE k = kh*64 + t.
// w2c[32] regs; ~54 VGPR total -> no spill (launch_bounds cap ~84 is far
// above the working set, pure insurance). CHUNK=32 -> 5.6 KB LDS -> 28
// single-wave WGs/CU. h-compute duplicated across the 2 k-half blocks
// (~7% extra VALU) in exchange for ~4x occupancy vs round 0.
// Per-(a,k) accumulation order identical to round 0.
// ---------------------------------------------------------------------------
__global__ __launch_bounds__(64, 6) void d0_kernel(
    const float* __restrict__ rbf_s, const int* __restrict__ nbrs_s,
    const int* __restrict__ off,
    const float* __restrict__ w1, const float* __restrict__ b1,
    const float* __restrict__ w2, const float* __restrict__ b2,
    const float* __restrict__ emix,
    const float* __restrict__ G0,
    float* __restrict__ V)
{
    __shared__ float s_w1[NB][RH];
    __shared__ float s_b1v[RH];
    __shared__ float s_h[CHUNK][RH];
    __shared__ int   s_nbr[CHUNK];

    int t = threadIdx.x;              // 0..63
    for (int idx = t; idx < NB * RH; idx += 64)
        s_w1[idx >> 5][idx & 31] = w1[idx];
    if (t < RH) s_b1v[t] = b1[t];
    __syncthreads();

    int bid = blockIdx.x;
    int a   = bid >> 1;
    int kh  = bid & 1;
    int k   = kh * 64 + t;            // the one k column this lane owns

    float w2c[RH];
    #pragma unroll
    for (int j = 0; j < RH; j++) w2c[j] = w2[j * (3 * KD) + k];
    float b2k = b2[k];

    int g = t >> 5, j = t & 31;       // 2 groups of 32 lanes for h compute
    float b1j = s_b1v[j];
    int start = off[a], end = off[a + 1];

    float Dacc = 0.0f;
    for (int c = start; c < end; c += CHUNK) {
        int m = min(CHUNK, end - c);
        __syncthreads();
        for (int pr = g; pr < m; pr += 2) {
            const float* rb = rbf_s + (size_t)(c + pr) * NB;
            float acc = b1j;
            #pragma unroll
            for (int i = 0; i < NB; i++) acc += rb[i] * s_w1[i][j];
            s_h[pr][j] = silu(acc);
        }
        if (t < m) s_nbr[t] = nbrs_s[c + t];
        __syncthreads();

        float gv_next = G0[(size_t)s_nbr[0] * KD + k];
        for (int i = 0; i < m; i++) {
            float gv = gv_next;
            if (i + 1 < m) gv_next = G0[(size_t)s_nbr[i + 1] * KD + k];
            float R = b2k;
            #pragma unroll
            for (int jq = 0; jq < RH / 4; jq++) {
                float4 h4 = *(const float4*)&s_h[i][4 * jq];
                R += h4.x * w2c[4 * jq + 0] + h4.y * w2c[4 * jq + 1]
                   + h4.z * w2c[4 * jq + 2] + h4.w * w2c[4 * jq + 3];
            }
            Dacc += R * gv;
        }
    }
    float n0 = G0[(size_t)a * KD + k] + C2 * Dacc;
    V[(size_t)a * KD + k] = n0 + n0 * n0 * emix[k];
}

// ---------------------------------------------------------------------------
// K6: head MLP, 8 atoms per block (625 blocks for occupancy).
// ---------------------------------------------------------------------------
__global__ __launch_bounds__(128) void head_kernel(
    const float* __restrict__ V,
    const float* __restrict__ w1, const float* __restrict__ b1,
    const float* __restrict__ w2, const float* __restrict__ b2,
    const float* __restrict__ lw, const float* __restrict__ lb,
    float* __restrict__ out)
{
    __shared__ float s_a[8][KD];
    __shared__ float s_b[8][KD];
    int j = threadIdx.x;
    int abase = blockIdx.x * 8;

    #pragma unroll
    for (int a = 0; a < 8; a++) {
        int ga = abase + a;
        s_a[a][j] = (ga < kAtoms) ? V[(size_t)ga * KD + j] : 0.0f;
    }
    __syncthreads();

    float acc[8];
    float bj = b1[j];
    #pragma unroll
    for (int a = 0; a < 8; a++) acc[a] = bj;
    for (int kk = 0; kk < KD; kk += 4) {
        float wa = w1[(kk + 0) * KD + j], wb = w1[(kk + 1) * KD + j];
        float wc = w1[(kk + 2) * KD + j], wd = w1[(kk + 3) * KD + j];
        #pragma unroll
        for (int a = 0; a < 8; a++) {
            float4 v = *(const float4*)&s_a[a][kk];
            acc[a] += v.x * wa + v.y * wb + v.z * wc + v.w * wd;
        }
    }
    #pragma unroll
    for (int a = 0; a < 8; a++) s_b[a][j] = silu(acc[a]);
    __syncthreads();

    float b2j = b2[j];
    #pragma unroll
    for (int a = 0; a < 8; a++) acc[a] = b2j;
    for (int kk = 0; kk < KD; kk += 4) {
        float wa = w2[(kk + 0) * KD + j], wb = w2[(kk + 1) * KD + j];
        float wc = w2[(kk + 2) * KD + j], wd = w2[(kk + 3) * KD + j];
        #pragma unroll
        for (int a = 0; a < 8; a++) {
            float4 v = *(const float4*)&s_b[a][kk];
            acc[a] += v.x * wa + v.y * wb + v.z * wc + v.w * wd;
        }
    }
    float lwj = lw[j];
    __syncthreads();
    #pragma unroll
    for (int a = 0; a < 8; a++) s_a[a][j] = silu(acc[a]) * lwj;
    __syncthreads();
    for (int s = 64; s > 0; s >>= 1) {
        if (j < s) {
            #pragma unroll
            for (int a = 0; a < 8; a++) s_a[a][j] += s_a[a][j + s];
        }
        __syncthreads();
    }
    if (j < 8) {
        int ga = abase + j;
        if (ga < kAtoms) out[ga] = s_a[j][0] + lb[0];
    }
}

// ---------------------------------------------------------------------------
extern "C" void kernel_launch(void* const* d_in, const int* in_sizes, int n_in,
                              void* d_out, int out_size, void* d_ws, size_t ws_size,
                              hipStream_t stream) {
    const float* positions = (const float*)d_in[0];
    const float* cells     = (const float*)d_in[1];
    const int*   species   = (const int*)d_in[2];
    const int*   shifts    = (const int*)d_in[3];
    const int*   ctr       = (const int*)d_in[4];
    const int*   nbr       = (const int*)d_in[5];
    const int*   spair     = (const int*)d_in[6];
    const float* embed     = (const float*)d_in[7];
    const float* rad_w1    = (const float*)d_in[8];
    const float* rad_b1    = (const float*)d_in[9];
    const float* rad_w2    = (const float*)d_in[10];
    const float* rad_b2    = (const float*)d_in[11];
    const float* erad_w1   = (const float*)d_in[12];
    const float* erad_b1   = (const float*)d_in[13];
    const float* erad_w2   = (const float*)d_in[14];
    const float* erad_b2   = (const float*)d_in[15];
    const float* mix_a     = (const float*)d_in[16];
    const float* emix_a    = (const float*)d_in[17];
    const float* head_w1   = (const float*)d_in[18];
    const float* head_b1   = (const float*)d_in[19];
    const float* head_w2   = (const float*)d_in[20];
    const float* head_b2   = (const float*)d_in[21];
    const float* last_w    = (const float*)d_in[22];
    const float* last_b    = (const float*)d_in[23];
    // U2 (d_in[24]) unused: l>=1 channels are dead code for the output.

    float* rbf_s = (float*)d_ws;                          // 160000*8
    float* G0    = rbf_s + (size_t)kPairs * NB;           // 5000*128
    float* V     = G0    + (size_t)kAtoms * KD;           // 5000*128
    int*   cnt   = (int*)(V + (size_t)kAtoms * KD);       // 5000
    int*   off   = cnt + kAtoms;                          // 5001
    int*   cur   = off + kAtoms + 1;                      // 5000
    int*   nbrs  = cur + kAtoms;                          // 160000
    int*   specs = nbrs + kPairs;                         // 160000

    hipMemsetAsync(cnt, 0, kAtoms * sizeof(int), stream);

    hist_kernel<<<kPairs / 256, 256, 0, stream>>>(ctr, cnt);
    scan_kernel<<<1, 1024, 0, stream>>>(cnt, off, cur);
    build_kernel<<<kPairs / 256, 256, 0, stream>>>(
        positions, cells, species, shifts, ctr, nbr, spair,
        cur, nbrs, specs, rbf_s);

    f0_kernel<<<kAtoms / 2, 128, 0, stream>>>(
        rbf_s, specs, off, embed, rad_w1, rad_b1, rad_w2, rad_b2,
        mix_a, G0);

    d0_kernel<<<kAtoms * 2, 64, 0, stream>>>(
        rbf_s, nbrs, off, erad_w1, erad_b1, erad_w2, erad_b2,
        emix_a, G0, V);

    head_kernel<<<(kAtoms + 7) / 8, 128, 0, stream>>>(
        V, head_w1, head_b1, head_w2, head_b2, last_w, last_b,
        (float*)d_out);
}

// Round 4
// 223.727 us; speedup vs baseline: 1.0626x; 1.0626x over previous
//
#include <hip/hip_runtime.h>

// Problem constants
constexpr int   kAtoms  = 5000;
constexpr int   kPairs  = 160000;
constexpr int   KD      = 128;   // K
constexpr int   NB      = 8;     // N_BASIS
constexpr int   RH      = 32;    // RAD_HIDDEN
constexpr float kCutoff = 5.0f;
constexpr float kPi     = 3.14159265358979323846f;
constexpr float C1 = 0.2f * 0.1767767f;   // INIT_SCALE * MSG_SCALE
constexpr float C2 = 1.2f * 0.1767767f;   // (1+INIT_SCALE) * MSG_SCALE
constexpr int   CHUNK = 32;               // ~mean neighbor count (Poisson 32)

__device__ __forceinline__ float silu(float x) { return x / (1.0f + __expf(-x)); }

// Only the l=0 channel reaches the output; l>=1 / sph / U2 are dead code.
//   F0[a][k] = C1 * sum_p R0_p[k]*e_spec[k];  G0 = F0+F0^2*mix
//   D[a][k]  = sum_p Re0_p[k]*G0[nbr_p][k];   n = G0+C2*D;  V = n+n^2*emix
//   out = head MLP(V)
// GFX950 NOTE (learned rounds 1-3): __launch_bounds__(B, w) caps VGPRs at
// 256/w (256-reg addressable file, NOT 512). w>=6 -> 40-reg cap -> spill
// (WRITE_SIZE 13-123MB of scratch). Keep w <= 256/working_set.

// ---------------------------------------------------------------------------
__global__ __launch_bounds__(256) void hist_kernel(
    const int* __restrict__ ctr, int* __restrict__ cnt)
{
    int p = blockIdx.x * 256 + threadIdx.x;
    atomicAdd(cnt + ctr[p], 1);
}

// ---------------------------------------------------------------------------
__global__ __launch_bounds__(1024) void scan_kernel(
    const int* __restrict__ cnt, int* __restrict__ off, int* __restrict__ cur)
{
    __shared__ int s_part[1024];
    const int CH = 5;                       // 1024*5 = 5120 >= 5000
    int t = threadIdx.x;
    int base = t * CH;
    int loc[CH];
    int run = 0;
    #pragma unroll
    for (int i = 0; i < CH; i++) {
        int idx = base + i;
        int v = (idx < kAtoms) ? cnt[idx] : 0;
        loc[i] = run;
        run += v;
    }
    s_part[t] = run;
    __syncthreads();
    for (int st = 1; st < 1024; st <<= 1) {
        int v = (t >= st) ? s_part[t - st] : 0;
        __syncthreads();
        s_part[t] += v;
        __syncthreads();
    }
    int excl = (t > 0) ? s_part[t - 1] : 0;
    #pragma unroll
    for (int i = 0; i < CH; i++) {
        int idx = base + i;
        if (idx < kAtoms) { off[idx] = excl + loc[i]; cur[idx] = excl + loc[i]; }
    }
    if (t == 1023) off[kAtoms] = s_part[1023];
}

// ---------------------------------------------------------------------------
__global__ __launch_bounds__(256) void build_kernel(
    const float* __restrict__ pos, const float* __restrict__ cells,
    const int* __restrict__ species, const int* __restrict__ shifts,
    const int* __restrict__ ctr, const int* __restrict__ nbr,
    const int* __restrict__ spair,
    int* __restrict__ cur, int* __restrict__ nbrs_s, int* __restrict__ specs_s,
    float* __restrict__ rbf_s)
{
    int p = blockIdx.x * 256 + threadIdx.x;
    int ci = ctr[p], ni = nbr[p], sp = spair[p];
    float s0 = (float)shifts[p * 3 + 0] - 1.0f;
    float s1 = (float)shifts[p * 3 + 1] - 1.0f;
    float s2 = (float)shifts[p * 3 + 2] - 1.0f;
    const float* C = cells + sp * 9;
    float vx = pos[ni * 3 + 0] - pos[ci * 3 + 0] + s0 * C[0] + s1 * C[3] + s2 * C[6];
    float vy = pos[ni * 3 + 1] - pos[ci * 3 + 1] + s0 * C[1] + s1 * C[4] + s2 * C[7];
    float vz = pos[ni * 3 + 2] - pos[ci * 3 + 2] + s0 * C[2] + s1 * C[5] + s2 * C[8];
    float d = sqrtf(vx * vx + vy * vy + vz * vz + 1e-12f);
    float fcut = (d < kCutoff) ? 0.5f * (__cosf(kPi * d / kCutoff) + 1.0f) : 0.0f;

    int slot = atomicAdd(cur + ci, 1);
    nbrs_s[slot]  = ni;
    specs_s[slot] = species[ni];

    float r[NB];
    #pragma unroll
    for (int i = 0; i < NB; i++) {
        float tt = d - (kCutoff / (NB - 1)) * (float)i;
        r[i] = __expf(-2.0f * tt * tt) * fcut;
    }
    float4* dst = (float4*)(rbf_s + (size_t)slot * NB);
    dst[0] = make_float4(r[0], r[1], r[2], r[3]);
    dst[1] = make_float4(r[4], r[5], r[6], r[7]);
}

// ---------------------------------------------------------------------------
// K4: species-factored F0 + G0 store. 128 threads = 2 waves, one atom per
// wave (per-wave private LDS partials; all __syncthreads at uniform points).
// ---------------------------------------------------------------------------
__global__ __launch_bounds__(128) void f0_kernel(
    const float* __restrict__ rbf_s, const int* __restrict__ specs_s,
    const int* __restrict__ off,
    const float* __restrict__ embed,
    const float* __restrict__ w1, const float* __restrict__ b1,
    const float* __restrict__ w2, const float* __restrict__ b2,
    const float* __restrict__ mix,
    float* __restrict__ G0)
{
    __shared__ float s_w1[NB][RH];
    __shared__ float s_b1v[RH];
    __shared__ float s_Hp[2][2][4][RH];   // [wave][group][spec][j]
    __shared__ float s_H[2][4][RH];       // [wave][spec][j]
    __shared__ float s_np[2][2][4];
    __shared__ float s_nc[2][4];

    int t = threadIdx.x;          // 0..127
    int w = t >> 6;               // wave id (atom within block)
    int t64 = t & 63;
    for (int idx = t; idx < NB * RH; idx += 128)
        s_w1[idx >> 5][idx & 31] = w1[idx];
    if (t < RH) s_b1v[t] = b1[t];
    __syncthreads();

    int a = blockIdx.x * 2 + w;
    int start = off[a], m = off[a + 1] - start;

    int g = t64 >> 5, j = t64 & 31;
    float H0 = 0, H1 = 0, H2 = 0, H3 = 0;
    int   n0 = 0, n1 = 0, n2 = 0, n3 = 0;
    float b1j = s_b1v[j];
    for (int pr = g; pr < m; pr += 2) {
        const float* rb = rbf_s + (size_t)(start + pr) * NB;
        float acc = b1j;
        #pragma unroll
        for (int i = 0; i < NB; i++) acc += rb[i] * s_w1[i][j];
        float h = silu(acc);
        int s = specs_s[start + pr];
        H0 += (s == 0) ? h : 0.0f;  H1 += (s == 1) ? h : 0.0f;
        H2 += (s == 2) ? h : 0.0f;  H3 += (s == 3) ? h : 0.0f;
        n0 += (s == 0); n1 += (s == 1); n2 += (s == 2); n3 += (s == 3);
    }
    s_Hp[w][g][0][j] = H0; s_Hp[w][g][1][j] = H1;
    s_Hp[w][g][2][j] = H2; s_Hp[w][g][3][j] = H3;
    if (j == 0) {
        s_np[w][g][0] = (float)n0; s_np[w][g][1] = (float)n1;
        s_np[w][g][2] = (float)n2; s_np[w][g][3] = (float)n3;
    }
    __syncthreads();
    for (int e = t64; e < 4 * RH; e += 64) {
        int s = e >> 5, jj = e & 31;
        s_H[w][s][jj] = s_Hp[w][0][s][jj] + s_Hp[w][1][s][jj];
    }
    if (t64 < 4) s_nc[w][t64] = s_np[w][0][t64] + s_np[w][1][t64];
    __syncthreads();

    float nc0 = s_nc[w][0], nc1 = s_nc[w][1], nc2 = s_nc[w][2], nc3 = s_nc[w][3];
    #pragma unroll
    for (int half = 0; half < 2; half++) {
        int k = t64 + 64 * half;
        float e0 = embed[0 * KD + k], e1 = embed[1 * KD + k];
        float e2 = embed[2 * KD + k], e3 = embed[3 * KD + k];
        float P0 = 0, P1 = 0, P2 = 0, P3 = 0;
        #pragma unroll 2
        for (int jq = 0; jq < RH / 4; jq++) {
            float4 h0 = *(const float4*)&s_H[w][0][4 * jq];
            float4 h1 = *(const float4*)&s_H[w][1][4 * jq];
            float4 h2 = *(const float4*)&s_H[w][2][4 * jq];
            float4 h3 = *(const float4*)&s_H[w][3][4 * jq];
            float wa = w2[(4 * jq + 0) * (3 * KD) + k];
            float wb = w2[(4 * jq + 1) * (3 * KD) + k];
            float wc = w2[(4 * jq + 2) * (3 * KD) + k];
            float wd = w2[(4 * jq + 3) * (3 * KD) + k];
            P0 += h0.x * wa + h0.y * wb + h0.z * wc + h0.w * wd;
            P1 += h1.x * wa + h1.y * wb + h1.z * wc + h1.w * wd;
            P2 += h2.x * wa + h2.y * wb + h2.z * wc + h2.w * wd;
            P3 += h3.x * wa + h3.y * wb + h3.z * wc + h3.w * wd;
        }
        float F = b2[k] * (nc0 * e0 + nc1 * e1 + nc2 * e2 + nc3 * e3)
                + e0 * P0 + e1 * P1 + e2 * P2 + e3 * P3;
        float F0v = C1 * F;
        G0[(size_t)a * KD + k] = F0v + F0v * F0v * mix[k];
    }
}

// ---------------------------------------------------------------------------
// K5: D0 + V. Round-0 structure: 64 threads (1 wave) per atom, each lane
// owns TWO k columns (k, k+64) -> 64 FMAs per pair against 8 ds_read_b128
// (FMA-bound ratio; split-k variants were LDS-issue-bound). Fixes vs round 0:
//   - CHUNK 96->32: LDS 13.8KB->5.6KB, so occupancy is VGPR-limited at
//     16 waves/CU instead of LDS-limited at 11.
//   - __launch_bounds__(64, 2): VGPR cap 256/2=128 >> working set (~90),
//     guaranteed no spill (w>=6 capped at 40 and spilled, rounds 1-3).
//   - 1-step prefetch of both G0 gathers hides L2 latency under the dot.
// Per-(a,k) accumulation order identical to round 0 -> absmax 0.0.
// ---------------------------------------------------------------------------
__global__ __launch_bounds__(64, 2) void d0_kernel(
    const float* __restrict__ rbf_s, const int* __restrict__ nbrs_s,
    const int* __restrict__ off,
    const float* __restrict__ w1, const float* __restrict__ b1,
    const float* __restrict__ w2, const float* __restrict__ b2,
    const float* __restrict__ emix,
    const float* __restrict__ G0,
    float* __restrict__ V)
{
    __shared__ float s_w1[NB][RH];
    __shared__ float s_b1v[RH];
    __shared__ float s_h[CHUNK][RH];
    __shared__ int   s_nbr[CHUNK];

    int t = threadIdx.x;              // 0..63
    for (int idx = t; idx < NB * RH; idx += 64)
        s_w1[idx >> 5][idx & 31] = w1[idx];
    if (t < RH) s_b1v[t] = b1[t];
    __syncthreads();

    int a = blockIdx.x;
    int start = off[a], end = off[a + 1];
    int k0 = t, k1 = t + 64;

    float w2c0[RH], w2c1[RH];
    #pragma unroll
    for (int j = 0; j < RH; j++) {
        w2c0[j] = w2[j * (3 * KD) + k0];
        w2c1[j] = w2[j * (3 * KD) + k1];
    }
    float b2k0 = b2[k0], b2k1 = b2[k1];

    int g = t >> 5, j = t & 31;
    float b1j = s_b1v[j];

    float Dacc0 = 0.0f, Dacc1 = 0.0f;
    for (int c = start; c < end; c += CHUNK) {
        int m = min(CHUNK, end - c);
        __syncthreads();
        for (int pr = g; pr < m; pr += 2) {
            const float* rb = rbf_s + (size_t)(c + pr) * NB;
            float acc = b1j;
            #pragma unroll
            for (int i = 0; i < NB; i++) acc += rb[i] * s_w1[i][j];
            s_h[pr][j] = silu(acc);
        }
        if (t < m) s_nbr[t] = nbrs_s[c + t];
        __syncthreads();

        const float* gb = G0 + (size_t)s_nbr[0] * KD;
        float gv0_next = gb[k0];
        float gv1_next = gb[k1];
        for (int i = 0; i < m; i++) {
            float gv0 = gv0_next, gv1 = gv1_next;
            if (i + 1 < m) {
                const float* gn = G0 + (size_t)s_nbr[i + 1] * KD;
                gv0_next = gn[k0];
                gv1_next = gn[k1];
            }
            float R0 = b2k0, R1 = b2k1;
            #pragma unroll
            for (int jq = 0; jq < RH / 4; jq++) {
                float4 h4 = *(const float4*)&s_h[i][4 * jq];
                R0 += h4.x * w2c0[4 * jq + 0] + h4.y * w2c0[4 * jq + 1]
                    + h4.z * w2c0[4 * jq + 2] + h4.w * w2c0[4 * jq + 3];
                R1 += h4.x * w2c1[4 * jq + 0] + h4.y * w2c1[4 * jq + 1]
                    + h4.z * w2c1[4 * jq + 2] + h4.w * w2c1[4 * jq + 3];
            }
            Dacc0 += R0 * gv0;
            Dacc1 += R1 * gv1;
        }
    }
    float n0 = G0[(size_t)a * KD + k0] + C2 * Dacc0;
    float n1 = G0[(size_t)a * KD + k1] + C2 * Dacc1;
    V[(size_t)a * KD + k0] = n0 + n0 * n0 * emix[k0];
    V[(size_t)a * KD + k1] = n1 + n1 * n1 * emix[k1];
}

// ---------------------------------------------------------------------------
// K6: head MLP, 8 atoms per block (625 blocks for occupancy).
// ---------------------------------------------------------------------------
__global__ __launch_bounds__(128) void head_kernel(
    const float* __restrict__ V,
    const float* __restrict__ w1, const float* __restrict__ b1,
    const float* __restrict__ w2, const float* __restrict__ b2,
    const float* __restrict__ lw, const float* __restrict__ lb,
    float* __restrict__ out)
{
    __shared__ float s_a[8][KD];
    __shared__ float s_b[8][KD];
    int j = threadIdx.x;
    int abase = blockIdx.x * 8;

    #pragma unroll
    for (int a = 0; a < 8; a++) {
        int ga = abase + a;
        s_a[a][j] = (ga < kAtoms) ? V[(size_t)ga * KD + j] : 0.0f;
    }
    __syncthreads();

    float acc[8];
    float bj = b1[j];
    #pragma unroll
    for (int a = 0; a < 8; a++) acc[a] = bj;
    for (int kk = 0; kk < KD; kk += 4) {
        float wa = w1[(kk + 0) * KD + j], wb = w1[(kk + 1) * KD + j];
        float wc = w1[(kk + 2) * KD + j], wd = w1[(kk + 3) * KD + j];
        #pragma unroll
        for (int a = 0; a < 8; a++) {
            float4 v = *(const float4*)&s_a[a][kk];
            acc[a] += v.x * wa + v.y * wb + v.z * wc + v.w * wd;
        }
    }
    #pragma unroll
    for (int a = 0; a < 8; a++) s_b[a][j] = silu(acc[a]);
    __syncthreads();

    float b2j = b2[j];
    #pragma unroll
    for (int a = 0; a < 8; a++) acc[a] = b2j;
    for (int kk = 0; kk < KD; kk += 4) {
        float wa = w2[(kk + 0) * KD + j], wb = w2[(kk + 1) * KD + j];
        float wc = w2[(kk + 2) * KD + j], wd = w2[(kk + 3) * KD + j];
        #pragma unroll
        for (int a = 0; a < 8; a++) {
            float4 v = *(const float4*)&s_b[a][kk];
            acc[a] += v.x * wa + v.y * wb + v.z * wc + v.w * wd;
        }
    }
    float lwj = lw[j];
    __syncthreads();
    #pragma unroll
    for (int a = 0; a < 8; a++) s_a[a][j] = silu(acc[a]) * lwj;
    __syncthreads();
    for (int s = 64; s > 0; s >>= 1) {
        if (j < s) {
            #pragma unroll
            for (int a = 0; a < 8; a++) s_a[a][j] += s_a[a][j + s];
        }
        __syncthreads();
    }
    if (j < 8) {
        int ga = abase + j;
        if (ga < kAtoms) out[ga] = s_a[j][0] + lb[0];
    }
}

// ---------------------------------------------------------------------------
extern "C" void kernel_launch(void* const* d_in, const int* in_sizes, int n_in,
                              void* d_out, int out_size, void* d_ws, size_t ws_size,
                              hipStream_t stream) {
    const float* positions = (const float*)d_in[0];
    const float* cells     = (const float*)d_in[1];
    const int*   species   = (const int*)d_in[2];
    const int*   shifts    = (const int*)d_in[3];
    const int*   ctr       = (const int*)d_in[4];
    const int*   nbr       = (const int*)d_in[5];
    const int*   spair     = (const int*)d_in[6];
    const float* embed     = (const float*)d_in[7];
    const float* rad_w1    = (const float*)d_in[8];
    const float* rad_b1    = (const float*)d_in[9];
    const float* rad_w2    = (const float*)d_in[10];
    const float* rad_b2    = (const float*)d_in[11];
    const float* erad_w1   = (const float*)d_in[12];
    const float* erad_b1   = (const float*)d_in[13];
    const float* erad_w2   = (const float*)d_in[14];
    const float* erad_b2   = (const float*)d_in[15];
    const float* mix_a     = (const float*)d_in[16];
    const float* emix_a    = (const float*)d_in[17];
    const float* head_w1   = (const float*)d_in[18];
    const float* head_b1   = (const float*)d_in[19];
    const float* head_w2   = (const float*)d_in[20];
    const float* head_b2   = (const float*)d_in[21];
    const float* last_w    = (const float*)d_in[22];
    const float* last_b    = (const float*)d_in[23];
    // U2 (d_in[24]) unused: l>=1 channels are dead code for the output.

    float* rbf_s = (float*)d_ws;                          // 160000*8
    float* G0    = rbf_s + (size_t)kPairs * NB;           // 5000*128
    float* V     = G0    + (size_t)kAtoms * KD;           // 5000*128
    int*   cnt   = (int*)(V + (size_t)kAtoms * KD);       // 5000
    int*   off   = cnt + kAtoms;                          // 5001
    int*   cur   = off + kAtoms + 1;                      // 5000
    int*   nbrs  = cur + kAtoms;                          // 160000
    int*   specs = nbrs + kPairs;                         // 160000

    hipMemsetAsync(cnt, 0, kAtoms * sizeof(int), stream);

    hist_kernel<<<kPairs / 256, 256, 0, stream>>>(ctr, cnt);
    scan_kernel<<<1, 1024, 0, stream>>>(cnt, off, cur);
    build_kernel<<<kPairs / 256, 256, 0, stream>>>(
        positions, cells, species, shifts, ctr, nbr, spair,
        cur, nbrs, specs, rbf_s);

    f0_kernel<<<kAtoms / 2, 128, 0, stream>>>(
        rbf_s, specs, off, embed, rad_w1, rad_b1, rad_w2, rad_b2,
        mix_a, G0);

    d0_kernel<<<kAtoms, 64, 0, stream>>>(
        rbf_s, nbrs, off, erad_w1, erad_b1, erad_w2, erad_b2,
        emix_a, G0, V);

    head_kernel<<<(kAtoms + 7) / 8, 128, 0, stream>>>(
        V, head_w1, head_b1, head_w2, head_b2, last_w, last_b,
        (float*)d_out);
}